// Round 1
// baseline (229.734 us; speedup 1.0000x reference)
//
#include <hip/hip_runtime.h>

typedef unsigned short u16;
typedef unsigned int   u32;
typedef __attribute__((ext_vector_type(8))) short s16x8;
typedef __attribute__((ext_vector_type(4))) float f32x4;
typedef __attribute__((ext_vector_type(4))) u32   u32x4;

#define DEV static __device__ __forceinline__

static constexpr int B_ = 256, C_ = 64, D_ = 256, H_ = 4096, O_ = 256, E_ = 4;

DEV u16 f2bf(float f) {
  u32 u = __builtin_bit_cast(u32, f);
  u += 0x7fffu + ((u >> 16) & 1u);   // round-to-nearest-even
  return (u16)(u >> 16);
}
DEV float bf2f(u16 u) { return __builtin_bit_cast(float, (u32)u << 16); }

DEV void async16(const u16* g, u16* l) {
  __builtin_amdgcn_global_load_lds(
      (const __attribute__((address_space(1))) void*)g,
      (__attribute__((address_space(3))) void*)l, 16, 0, 0);
}

// ---------------- convert f32 -> bf16, 8 elems/thread ----------------
__global__ void k_cvt(const float* __restrict__ src, u16* __restrict__ dst) {
  const int i = blockIdx.x * blockDim.x + threadIdx.x;
  const f32x4 a = ((const f32x4*)src)[2 * i];
  const f32x4 b = ((const f32x4*)src)[2 * i + 1];
  u32x4 o;
  o[0] = (u32)f2bf(a[0]) | ((u32)f2bf(a[1]) << 16);
  o[1] = (u32)f2bf(a[2]) | ((u32)f2bf(a[3]) << 16);
  o[2] = (u32)f2bf(b[0]) | ((u32)f2bf(b[1]) << 16);
  o[3] = (u32)f2bf(b[2]) | ((u32)f2bf(b[3]) << 16);
  ((u32x4*)dst)[i] = o;
}

// ------------- per-expert slab transpose: f32 [R][C] -> bf16 [C][R] -------------
__global__ void k_transpose(const float* __restrict__ src, u16* __restrict__ dst,
                            const int R, const int Cc) {
  __shared__ float tile[64][65];   // +1 pad: bank-conflict-free
  const int nct = Cc >> 6, nrt = R >> 6;
  int bx = blockIdx.x;
  const int ct = bx % nct; bx /= nct;
  const int rt = bx % nrt; const int e = bx / nrt;
  const float* s = src + (size_t)e * R * Cc;
  u16* d = dst + (size_t)e * R * Cc;
  const int tx = threadIdx.x & 63, ty = threadIdx.x >> 6;
  #pragma unroll
  for (int i = 0; i < 64; i += 4)
    tile[i + ty][tx] = s[(size_t)(rt * 64 + i + ty) * Cc + ct * 64 + tx];
  __syncthreads();
  #pragma unroll
  for (int i = 0; i < 64; i += 4) {
    const int cc = i + ty;
    d[(size_t)(ct * 64 + cc) * R + rt * 64 + tx] = f2bf(tile[tx][cc]);
  }
}

// ---------------- MFMA GEMM (m97 structure, swizzled global_load_lds) ----------------
// A: token-major bf16, row stride C_*K, block base c*K (rows are b-values for fixed c)
// Bw: transposed weights bf16 [E][N][K] (K contiguous)
// MODE 1: out = h bf16 (+b1), fused per-expert sum/sumsq atomics
// MODE 2: out = f32 (+b2) to d_out
template<int BM, int BN, int MODE>
__global__ __launch_bounds__(256)
void k_gemm(const u16* __restrict__ A, const u16* __restrict__ Bw,
            const int* __restrict__ proj, const float* __restrict__ bias,
            u16* __restrict__ outH, float* __restrict__ outF,
            float* __restrict__ s1g, float* __restrict__ s2g,
            const int K, const int N) {
  constexpr int WTM = BM / 2, WTN = BN / 2;       // 2x2 waves
  constexpr int FM = WTM / 16, FN = WTN / 16;
  constexpr int SA = BM * 4, SB = BN * 4;         // 16B slots per tile
  const int NT = N / BN, BT = B_ / BM;
  __shared__ __align__(16) u16 lds[(BM + BN) * 32];
  u16* ldsA = lds;
  u16* ldsB = lds + BM * 32;

  const int tid = threadIdx.x;
  const int l = tid & 63, w = tid >> 6;
  const int wm = w >> 1, wn = w & 1;

  int bx = blockIdx.x;
  const int nt = bx % NT; bx /= NT;
  const int bt = bx % BT; const int c = bx / BT;
  const int e = proj[c];

  const size_t rowStride = (size_t)C_ * K;
  const u16* Ab = A + (size_t)c * K + (size_t)bt * BM * rowStride;
  const u16* Bb = Bw + ((size_t)e * N + (size_t)nt * BN) * K;

  f32x4 acc[FM][FN];
  #pragma unroll
  for (int m = 0; m < FM; ++m)
    #pragma unroll
    for (int n = 0; n < FN; ++n)
      acc[m][n] = (f32x4){0.f, 0.f, 0.f, 0.f};

  const int KT = K >> 5;
  for (int kt = 0; kt < KT; ++kt) {
    const int k0 = kt << 5;
    // stage A: physical slot s -> row=s>>2, logical kslot=(s&3)^((s>>3)&3)
    // (inverse-swizzled SOURCE + linear LDS dest; reads apply same XOR -> 2-way max)
    #pragma unroll
    for (int i = 0; i < SA / 256; ++i) {
      const int s = i * 256 + tid;
      const int row = s >> 2;
      const int kl = ((s & 3) ^ ((s >> 3) & 3)) << 3;
      async16(Ab + (size_t)row * rowStride + (k0 + kl), ldsA + s * 8);
    }
    #pragma unroll
    for (int i = 0; i < SB / 256; ++i) {
      const int s = i * 256 + tid;
      const int col = s >> 2;
      const int kl = ((s & 3) ^ ((s >> 3) & 3)) << 3;
      async16(Bb + (size_t)col * K + (k0 + kl), ldsB + s * 8);
    }
    asm volatile("s_waitcnt vmcnt(0)" ::: "memory");
    __syncthreads();

    s16x8 av[FM], bv[FN];
    #pragma unroll
    for (int m = 0; m < FM; ++m) {
      const int r = wm * WTM + m * 16 + (l & 15);
      const int slot = (r << 2) | ((l >> 4) ^ ((r >> 1) & 3));
      av[m] = *(const s16x8*)(ldsA + slot * 8);
    }
    #pragma unroll
    for (int n = 0; n < FN; ++n) {
      const int cc = wn * WTN + n * 16 + (l & 15);
      const int slot = (cc << 2) | ((l >> 4) ^ ((cc >> 1) & 3));
      bv[n] = *(const s16x8*)(ldsB + slot * 8);
    }
    #pragma unroll
    for (int m = 0; m < FM; ++m)
      #pragma unroll
      for (int n = 0; n < FN; ++n)
        acc[m][n] = __builtin_amdgcn_mfma_f32_16x16x32_bf16(av[m], bv[n], acc[m][n], 0, 0, 0);
    __syncthreads();
  }

  // epilogue: C/D layout col=l&15, row=(l>>4)*4+i  [m89-verified]
  #pragma unroll
  for (int n = 0; n < FN; ++n) {
    const int colg = nt * BN + wn * WTN + n * 16 + (l & 15);
    const float bval = bias[e * N + colg];
    float p1 = 0.f, p2 = 0.f;
    #pragma unroll
    for (int m = 0; m < FM; ++m) {
      #pragma unroll
      for (int i = 0; i < 4; ++i) {
        const int rg = bt * BM + wm * WTM + m * 16 + (l >> 4) * 4 + i;
        const float v = acc[m][n][i] + bval;
        if constexpr (MODE == 1) {
          outH[((size_t)rg * C_ + c) * N + colg] = f2bf(v);
          p1 += v; p2 += v * v;
        } else {
          outF[((size_t)rg * C_ + c) * N + colg] = v;
        }
      }
    }
    if constexpr (MODE == 1) {
      // reduce over the 4 row-groups (lanes l, l^16, l^32, l^48 share colg)
      p1 += __shfl_xor(p1, 16); p1 += __shfl_xor(p1, 32);
      p2 += __shfl_xor(p2, 16); p2 += __shfl_xor(p2, 32);
      if (l < 16) {
        atomicAdd(&s1g[e * N + colg], p1);
        atomicAdd(&s2g[e * N + colg], p2);
      }
    }
  }
}

// ---------------- BN finalize: scale/shift per [E][H] ----------------
__global__ void k_finalize(const float* __restrict__ s1, const float* __restrict__ s2,
                           const int* __restrict__ proj, const float* __restrict__ gamma,
                           const float* __restrict__ beta, float* __restrict__ scale,
                           float* __restrict__ shift) {
  const int i = blockIdx.x * 256 + threadIdx.x;   // over E*H
  const int e = i >> 12;                          // H = 4096
  int cn = 0;
  #pragma unroll
  for (int c = 0; c < C_; ++c) cn += (proj[c] == e) ? 1 : 0;
  const float cnt = fmaxf((float)cn * (float)B_, 1.f);
  const float mean = s1[i] / cnt;
  const float var = s2[i] / cnt - mean * mean;    // biased (train-mode BN)
  const float inv = rsqrtf(var + 1e-5f);
  const float sc = inv * gamma[i];
  scale[i] = sc;
  shift[i] = beta[i] - mean * sc;
}

// ---------------- in-place normalize + ReLU (vec-8) ----------------
__global__ void k_apply(u16* __restrict__ h, const int* __restrict__ proj,
                        const float* __restrict__ scale, const float* __restrict__ shift) {
  const size_t i = (size_t)blockIdx.x * 256 + threadIdx.x;
  const size_t base = i * 8;
  const int t = (int)(base >> 12);
  const int k = (int)(base & 4095);
  const int e = proj[t & 63];
  const float* sc = scale + e * H_ + k;
  const float* sh = shift + e * H_ + k;
  const u32x4 raw = *(const u32x4*)(h + base);
  const f32x4 sc0 = *(const f32x4*)sc, sc1 = *(const f32x4*)(sc + 4);
  const f32x4 sh0 = *(const f32x4*)sh, sh1 = *(const f32x4*)(sh + 4);
  u16 rr[8];
  #pragma unroll
  for (int j = 0; j < 8; ++j) {
    const u16 hv = (u16)((raw[j >> 1] >> ((j & 1) * 16)) & 0xffffu);
    const float s = (j < 4) ? sc0[j & 3] : sc1[j & 3];
    const float b = (j < 4) ? sh0[j & 3] : sh1[j & 3];
    rr[j] = f2bf(fmaxf(bf2f(hv) * s + b, 0.f));
  }
  u32x4 o;
  o[0] = (u32)rr[0] | ((u32)rr[1] << 16);
  o[1] = (u32)rr[2] | ((u32)rr[3] << 16);
  o[2] = (u32)rr[4] | ((u32)rr[5] << 16);
  o[3] = (u32)rr[6] | ((u32)rr[7] << 16);
  *(u32x4*)(h + base) = o;
}

// ---------------- mask_ids passthrough as f32 ----------------
__global__ void k_mask(const int* __restrict__ m, float* __restrict__ o) {
  const int i = blockIdx.x * 256 + threadIdx.x;
  o[i] = (float)m[i];
}

extern "C" void kernel_launch(void* const* d_in, const int* in_sizes, int n_in,
                              void* d_out, int out_size, void* d_ws, size_t ws_size,
                              hipStream_t stream) {
  const float* x     = (const float*)d_in[0];
  const int*   mask  = (const int*)d_in[1];
  const int*   proj  = (const int*)d_in[2];
  const float* W1    = (const float*)d_in[3];
  const float* b1    = (const float*)d_in[4];
  const float* gamma = (const float*)d_in[5];
  const float* beta  = (const float*)d_in[6];
  const float* W2    = (const float*)d_in[7];
  const float* b2    = (const float*)d_in[8];
  float* out = (float*)d_out;

  char* ws = (char*)d_ws;
  size_t off = 0;
  u16* hbuf = (u16*)(ws + off); off += (size_t)B_ * C_ * H_ * 2;   // 128 MB, h then a (in-place)
  u16* xb   = (u16*)(ws + off); off += (size_t)B_ * C_ * D_ * 2;   // 8 MB
  u16* w1t  = (u16*)(ws + off); off += (size_t)E_ * D_ * H_ * 2;   // 8 MB  [E][H][D]
  u16* w2t  = (u16*)(ws + off); off += (size_t)E_ * H_ * O_ * 2;   // 8 MB  [E][O][H]
  float* s1  = (float*)(ws + off); off += (size_t)E_ * H_ * 4;
  float* s2  = (float*)(ws + off); off += (size_t)E_ * H_ * 4;
  float* scl = (float*)(ws + off); off += (size_t)E_ * H_ * 4;
  float* shf = (float*)(ws + off); off += (size_t)E_ * H_ * 4;

  (void)hipMemsetAsync(s1, 0, (size_t)2 * E_ * H_ * 4, stream);  // s1+s2 contiguous

  k_cvt<<<2048, 256, 0, stream>>>(x, xb);                          // 4M elems
  k_transpose<<<E_ * 4 * 64, 256, 0, stream>>>(W1, w1t, D_, H_);   // [D][H]->[H][D]
  k_transpose<<<E_ * 64 * 4, 256, 0, stream>>>(W2, w2t, H_, O_);   // [H][O]->[O][H]

  // GEMM1: 128x128 tile, grid = C * (B/128) * (H/128) = 4096 blocks
  k_gemm<128, 128, 1><<<C_ * 2 * 32, 256, 0, stream>>>(
      xb, w1t, proj, b1, hbuf, nullptr, s1, s2, D_, H_);

  k_finalize<<<E_ * H_ / 256, 256, 0, stream>>>(s1, s2, proj, gamma, beta, scl, shf);

  k_apply<<<(int)((size_t)B_ * C_ * H_ / 8 / 256), 256, 0, stream>>>(hbuf, proj, scl, shf);

  // GEMM2: 64x128 tile, grid = C * (B/64) * (O/128) = 512 blocks
  k_gemm<64, 128, 2><<<C_ * 4 * 2, 256, 0, stream>>>(
      hbuf, w2t, proj, b2, nullptr, out, nullptr, nullptr, H_, O_);

  k_mask<<<B_ * C_ / 256, 256, 0, stream>>>(mask, out + (size_t)B_ * C_ * O_);
}

// Round 2
// 182.095 us; speedup vs baseline: 1.2616x; 1.2616x over previous
//
#include <hip/hip_runtime.h>

typedef unsigned short u16;
typedef unsigned int   u32;
typedef __attribute__((ext_vector_type(8))) short s16x8;
typedef __attribute__((ext_vector_type(4))) float f32x4;
typedef __attribute__((ext_vector_type(4))) u32   u32x4;

#define DEV static __device__ __forceinline__

static constexpr int B_ = 256, C_ = 64, D_ = 256, H_ = 4096, O_ = 256, E_ = 4;

DEV u16 f2bf(float f) {
  u32 u = __builtin_bit_cast(u32, f);
  u += 0x7fffu + ((u >> 16) & 1u);   // RNE
  return (u16)(u >> 16);
}
DEV float bf2f(u16 u) { return __builtin_bit_cast(float, (u32)u << 16); }

DEV void async16(const u16* g, u16* l) {
  __builtin_amdgcn_global_load_lds(
      (const __attribute__((address_space(1))) void*)g,
      (__attribute__((address_space(3))) void*)l, 16, 0, 0);
}

DEV int xcd_swz(int bid, int nwg) { return (bid & 7) * (nwg >> 3) + (bid >> 3); }

// ---------------- convert f32 -> bf16, 8 elems/thread ----------------
__global__ void k_cvt(const float* __restrict__ src, u16* __restrict__ dst) {
  const int i = blockIdx.x * blockDim.x + threadIdx.x;
  const f32x4 a = ((const f32x4*)src)[2 * i];
  const f32x4 b = ((const f32x4*)src)[2 * i + 1];
  u32x4 o;
  o[0] = (u32)f2bf(a[0]) | ((u32)f2bf(a[1]) << 16);
  o[1] = (u32)f2bf(a[2]) | ((u32)f2bf(a[3]) << 16);
  o[2] = (u32)f2bf(b[0]) | ((u32)f2bf(b[1]) << 16);
  o[3] = (u32)f2bf(b[2]) | ((u32)f2bf(b[3]) << 16);
  ((u32x4*)dst)[i] = o;
}

// ------------- per-expert slab transpose: f32 [R][C] -> bf16 [C][R] -------------
__global__ void k_transpose(const float* __restrict__ src, u16* __restrict__ dst,
                            const int R, const int Cc) {
  __shared__ float tile[64][65];
  const int nct = Cc >> 6, nrt = R >> 6;
  int bx = blockIdx.x;
  const int ct = bx % nct; bx /= nct;
  const int rt = bx % nrt; const int e = bx / nrt;
  const float* s = src + (size_t)e * R * Cc;
  u16* d = dst + (size_t)e * R * Cc;
  const int tx = threadIdx.x & 63, ty = threadIdx.x >> 6;
  #pragma unroll
  for (int i = 0; i < 64; i += 4)
    tile[i + ty][tx] = s[(size_t)(rt * 64 + i + ty) * Cc + ct * 64 + tx];
  __syncthreads();
  #pragma unroll
  for (int i = 0; i < 64; i += 4) {
    const int cc = i + ty;
    d[(size_t)(ct * 64 + cc) * R + rt * 64 + tx] = f2bf(tile[tx][cc]);
  }
}

// ---------------- channel rank by expert (deterministic counting sort) ----------------
__global__ void k_sortc(const int* __restrict__ proj, int* __restrict__ perm) {
  const int c = threadIdx.x;              // 64 threads
  const int e = proj[c];
  int rank = 0;
  for (int c2 = 0; c2 < C_; ++c2) {
    const int e2 = proj[c2];
    rank += (e2 < e) || (e2 == e && c2 < c);
  }
  perm[rank] = c;
}

// ---------------- GEMM1: h = x*W1 + b1, fused per-expert sum/sumsq ----------------
// A: x bf16 token-major; Bw: w1t [E][H][D] (K=D contiguous)
__global__ __launch_bounds__(256, 2)
void k_gemm1(const u16* __restrict__ A, const u16* __restrict__ Bw,
             const int* __restrict__ proj, const int* __restrict__ perm,
             const float* __restrict__ bias,
             u16* __restrict__ outH, float* __restrict__ s1g, float* __restrict__ s2g) {
  constexpr int BM = 128, BN = 128, BK = 64, KT = D_ / BK;   // 4 K-steps
  constexpr int SA = BM * BK / 8, SB = BN * BK / 8;          // 1024, 1024 16B-slots
  constexpr int BUF = (SA + SB) * 8;                         // u16 per buffer
  __shared__ __align__(16) u16 lds[2 * BUF];                 // 64 KB
  const int tid = threadIdx.x, l = tid & 63, w = tid >> 6, wm = w >> 1, wn = w & 1;

  int bid = xcd_swz(blockIdx.x, gridDim.x);
  constexpr int NT = H_ / BN, BT = B_ / BM;                  // 32, 2
  const int nt = bid % NT; bid /= NT;
  const int bt = bid % BT; const int ci = bid / BT;
  const int c = perm[ci];
  const int e = proj[c];

  const size_t rsA = (size_t)C_ * D_;
  const u16* Ab = A + (size_t)c * D_ + (size_t)bt * BM * rsA;
  const u16* Bb = Bw + ((size_t)e * H_ + (size_t)nt * BN) * D_;

  f32x4 acc[4][4] = {};

  auto stage = [&](int kt) {
    const int k0 = kt * BK;
    u16* dst = lds + (kt & 1) * BUF;
    #pragma unroll
    for (int i = 0; i < SA / 256; ++i) {
      const int s = i * 256 + tid, row = s >> 3, j = (s & 7) ^ (row & 7);
      async16(Ab + (size_t)row * rsA + k0 + j * 8, dst + s * 8);
    }
    #pragma unroll
    for (int i = 0; i < SB / 256; ++i) {
      const int s = i * 256 + tid, col = s >> 3, j = (s & 7) ^ (col & 7);
      async16(Bb + (size_t)col * D_ + k0 + j * 8, dst + SA * 8 + s * 8);
    }
  };

  stage(0);
  asm volatile("s_waitcnt vmcnt(0)" ::: "memory");
  __builtin_amdgcn_s_barrier();

  #pragma unroll
  for (int kt = 0; kt < KT; ++kt) {
    if (kt + 1 < KT) stage(kt + 1);          // prefetch overlaps compute below
    const u16* bufA = lds + (kt & 1) * BUF;
    const u16* bufB = bufA + SA * 8;
    s16x8 av[2][4], bv[2][4];
    #pragma unroll
    for (int kk = 0; kk < 2; ++kk) {
      #pragma unroll
      for (int m = 0; m < 4; ++m) {
        const int r = wm * 64 + m * 16 + (l & 15), p = (kk * 4 + (l >> 4)) ^ (r & 7);
        av[kk][m] = *(const s16x8*)(bufA + (r * 8 + p) * 8);
      }
      #pragma unroll
      for (int n = 0; n < 4; ++n) {
        const int cc = wn * 64 + n * 16 + (l & 15), p = (kk * 4 + (l >> 4)) ^ (cc & 7);
        bv[kk][n] = *(const s16x8*)(bufB + (cc * 8 + p) * 8);
      }
    }
    #pragma unroll
    for (int kk = 0; kk < 2; ++kk)
      #pragma unroll
      for (int m = 0; m < 4; ++m)
        #pragma unroll
        for (int n = 0; n < 4; ++n)
          acc[m][n] = __builtin_amdgcn_mfma_f32_16x16x32_bf16(av[kk][m], bv[kk][n], acc[m][n], 0, 0, 0);
    asm volatile("s_waitcnt vmcnt(0) lgkmcnt(0)" ::: "memory");
    __builtin_amdgcn_s_barrier();
  }

  // epilogue: bias + stats + bf16 pack into LDS (XOR 16B-slot swizzle), then 16B stores
  u16* ldsOut = lds;   // 32 KB region, free after final barrier
  #pragma unroll
  for (int n = 0; n < 4; ++n) {
    const int colL = wn * 64 + n * 16 + (l & 15);
    const int colg = nt * BN + colL;
    const float bval = bias[e * H_ + colg];
    float p1 = 0.f, p2 = 0.f;
    #pragma unroll
    for (int m = 0; m < 4; ++m) {
      const int rbase = wm * 64 + m * 16 + (l >> 4) * 4;
      #pragma unroll
      for (int i = 0; i < 4; ++i) {
        const float v = acc[m][n][i] + bval;
        p1 += v; p2 += v * v;
        const int row = rbase + i;
        const int phys = (colL >> 3) ^ (row & 15);
        ldsOut[row * 128 + phys * 8 + (colL & 7)] = f2bf(v);
      }
    }
    p1 += __shfl_xor(p1, 16); p1 += __shfl_xor(p1, 32);
    p2 += __shfl_xor(p2, 16); p2 += __shfl_xor(p2, 32);
    if (l < 16) {
      atomicAdd(&s1g[e * H_ + colg], p1);
      atomicAdd(&s2g[e * H_ + colg], p2);
    }
  }
  __syncthreads();
  u16* outB = outH + ((size_t)(bt * BM) * C_ + c) * H_ + nt * BN;
  #pragma unroll
  for (int pass = 0; pass < 8; ++pass) {
    const int row = pass * 16 + (tid >> 4), sl = tid & 15;
    const u32x4 v = *(const u32x4*)(ldsOut + row * 128 + ((sl ^ (row & 15)) * 8));
    *(u32x4*)(outB + (size_t)row * C_ * H_ + sl * 8) = v;
  }
}

// ---------------- BN finalize -> bf16 scale/shift ----------------
__global__ void k_finalize(const float* __restrict__ s1, const float* __restrict__ s2,
                           const int* __restrict__ proj, const float* __restrict__ gamma,
                           const float* __restrict__ beta,
                           u16* __restrict__ sclB, u16* __restrict__ shfB) {
  const int i = blockIdx.x * 256 + threadIdx.x;   // over E*H
  const int e = i >> 12;                          // H = 4096
  int cn = 0;
  #pragma unroll
  for (int c = 0; c < C_; ++c) cn += (proj[c] == e) ? 1 : 0;
  const float cnt = fmaxf((float)cn * (float)B_, 1.f);
  const float mean = s1[i] / cnt;
  const float var = s2[i] / cnt - mean * mean;    // biased (train-mode BN)
  const float sc = rsqrtf(var + 1e-5f) * gamma[i];
  sclB[i] = f2bf(sc);
  shfB[i] = f2bf(beta[i] - mean * sc);
}

// ---------------- GEMM2: out = relu(scale*h+shift)*W2 + b2, apply fused on A-path ----------------
// A: h bf16 token-major; Bw: w2t [E][O][H] (K=H contiguous)
__global__ __launch_bounds__(256, 1)
void k_gemm2(const u16* __restrict__ A, const u16* __restrict__ Bw,
             const int* __restrict__ proj, const int* __restrict__ perm,
             const float* __restrict__ b2,
             const u16* __restrict__ scB, const u16* __restrict__ shB,
             float* __restrict__ outF) {
  constexpr int BM = 64, BN = 256, BK = 64, KT = H_ / BK;    // 64 K-steps
  constexpr int SA = BM * BK / 8, SB = BN * BK / 8;          // 512, 2048
  constexpr int BUF = (SA + SB) * 8;
  __shared__ __align__(16) u16 lds[2 * BUF];                 // 80 KB
  const int tid = threadIdx.x, l = tid & 63, w = tid >> 6;   // w = N-warp

  int bid = xcd_swz(blockIdx.x, gridDim.x);
  const int bt = bid % (B_ / BM); const int ci = bid / (B_ / BM);
  const int c = perm[ci];
  const int e = proj[c];

  const size_t rsA = (size_t)C_ * H_;
  const u16* Ab = A + (size_t)c * H_ + (size_t)bt * BM * rsA;
  const u16* Bb = Bw + (size_t)e * O_ * H_;
  const u16* scE = scB + e * H_;
  const u16* shE = shB + e * H_;

  f32x4 acc[4][4] = {};
  s16x8 hA[2], sA[2], tA[2];

  auto Aissue = [&](int kt) {          // issue-early: h + scale + shift to regs
    const int k0 = kt * BK;
    #pragma unroll
    for (int i = 0; i < 2; ++i) {
      const int s = i * 256 + tid, row = s >> 3, j = (s & 7) ^ (row & 7), k = k0 + j * 8;
      hA[i] = *(const s16x8*)(Ab + (size_t)row * rsA + k);
      sA[i] = *(const s16x8*)(scE + k);
      tA[i] = *(const s16x8*)(shE + k);
    }
  };
  auto Bissue = [&](int kt) {
    const int k0 = kt * BK;
    u16* dst = lds + (kt & 1) * BUF + SA * 8;
    #pragma unroll
    for (int i = 0; i < 8; ++i) {
      const int s = i * 256 + tid, col = s >> 3, j = (s & 7) ^ (col & 7);
      async16(Bb + (size_t)col * H_ + k0 + j * 8, dst + s * 8);
    }
  };
  auto Awrite = [&](int kt) {          // write-late: BN apply + ReLU + bf16 pack
    u16* dst = lds + (kt & 1) * BUF;
    #pragma unroll
    for (int i = 0; i < 2; ++i) {
      const int s = i * 256 + tid;
      u32x4 o;
      #pragma unroll
      for (int jj = 0; jj < 4; ++jj) {
        const float v0 = fmaxf(bf2f((u16)hA[i][2 * jj]) * bf2f((u16)sA[i][2 * jj]) + bf2f((u16)tA[i][2 * jj]), 0.f);
        const float v1 = fmaxf(bf2f((u16)hA[i][2 * jj + 1]) * bf2f((u16)sA[i][2 * jj + 1]) + bf2f((u16)tA[i][2 * jj + 1]), 0.f);
        o[jj] = (u32)f2bf(v0) | ((u32)f2bf(v1) << 16);
      }
      *(u32x4*)(dst + s * 8) = o;
    }
  };

  Aissue(0); Bissue(0); Awrite(0);
  asm volatile("s_waitcnt vmcnt(0) lgkmcnt(0)" ::: "memory");
  __builtin_amdgcn_s_barrier();

  #pragma unroll 2
  for (int kt = 0; kt < KT; ++kt) {
    if (kt + 1 < KT) { Aissue(kt + 1); Bissue(kt + 1); }
    const u16* bufA = lds + (kt & 1) * BUF;
    const u16* bufB = bufA + SA * 8;
    s16x8 av[2][4], bv[2][4];
    #pragma unroll
    for (int kk = 0; kk < 2; ++kk) {
      #pragma unroll
      for (int m = 0; m < 4; ++m) {
        const int r = m * 16 + (l & 15), p = (kk * 4 + (l >> 4)) ^ (r & 7);
        av[kk][m] = *(const s16x8*)(bufA + (r * 8 + p) * 8);
      }
      #pragma unroll
      for (int n = 0; n < 4; ++n) {
        const int cc = w * 64 + n * 16 + (l & 15), p = (kk * 4 + (l >> 4)) ^ (cc & 7);
        bv[kk][n] = *(const s16x8*)(bufB + (cc * 8 + p) * 8);
      }
    }
    #pragma unroll
    for (int kk = 0; kk < 2; ++kk)
      #pragma unroll
      for (int m = 0; m < 4; ++m)
        #pragma unroll
        for (int n = 0; n < 4; ++n)
          acc[m][n] = __builtin_amdgcn_mfma_f32_16x16x32_bf16(av[kk][m], bv[kk][n], acc[m][n], 0, 0, 0);
    if (kt + 1 < KT) Awrite(kt + 1);
    asm volatile("s_waitcnt vmcnt(0) lgkmcnt(0)" ::: "memory");
    __builtin_amdgcn_s_barrier();
  }

  #pragma unroll
  for (int n = 0; n < 4; ++n) {
    const int colg = w * 64 + n * 16 + (l & 15);
    const float bval = b2[e * O_ + colg];
    #pragma unroll
    for (int m = 0; m < 4; ++m) {
      #pragma unroll
      for (int i = 0; i < 4; ++i) {
        const int rg = bt * BM + m * 16 + (l >> 4) * 4 + i;
        outF[((size_t)rg * C_ + c) * O_ + colg] = acc[m][n][i] + bval;
      }
    }
  }
}

// ---------------- mask_ids passthrough as f32 ----------------
__global__ void k_mask(const int* __restrict__ m, float* __restrict__ o) {
  const int i = blockIdx.x * 256 + threadIdx.x;
  o[i] = (float)m[i];
}

extern "C" void kernel_launch(void* const* d_in, const int* in_sizes, int n_in,
                              void* d_out, int out_size, void* d_ws, size_t ws_size,
                              hipStream_t stream) {
  const float* x     = (const float*)d_in[0];
  const int*   mask  = (const int*)d_in[1];
  const int*   proj  = (const int*)d_in[2];
  const float* W1    = (const float*)d_in[3];
  const float* b1    = (const float*)d_in[4];
  const float* gamma = (const float*)d_in[5];
  const float* beta  = (const float*)d_in[6];
  const float* W2    = (const float*)d_in[7];
  const float* b2    = (const float*)d_in[8];
  float* out = (float*)d_out;

  char* ws = (char*)d_ws;
  size_t off = 0;
  u16* hbuf = (u16*)(ws + off); off += (size_t)B_ * C_ * H_ * 2;   // 128 MB
  u16* xb   = (u16*)(ws + off); off += (size_t)B_ * C_ * D_ * 2;   // 8 MB
  u16* w1t  = (u16*)(ws + off); off += (size_t)E_ * D_ * H_ * 2;   // 8 MB  [E][H][D]
  u16* w2t  = (u16*)(ws + off); off += (size_t)E_ * H_ * O_ * 2;   // 8 MB  [E][O][H]
  float* s1 = (float*)(ws + off); off += (size_t)E_ * H_ * 4;
  float* s2 = (float*)(ws + off); off += (size_t)E_ * H_ * 4;
  u16* sclB = (u16*)(ws + off); off += (size_t)E_ * H_ * 2;
  u16* shfB = (u16*)(ws + off); off += (size_t)E_ * H_ * 2;
  int* perm = (int*)(ws + off); off += 256;

  (void)hipMemsetAsync(s1, 0, (size_t)2 * E_ * H_ * 4, stream);   // s1+s2 contiguous

  k_sortc<<<1, 64, 0, stream>>>(proj, perm);
  k_cvt<<<2048, 256, 0, stream>>>(x, xb);
  k_transpose<<<E_ * 4 * 64, 256, 0, stream>>>(W1, w1t, D_, H_);   // [D][H]->[H][D]
  k_transpose<<<E_ * 64 * 4, 256, 0, stream>>>(W2, w2t, H_, O_);   // [H][O]->[O][H]

  k_gemm1<<<C_ * 2 * 32, 256, 0, stream>>>(xb, w1t, proj, perm, b1, hbuf, s1, s2);

  k_finalize<<<E_ * H_ / 256, 256, 0, stream>>>(s1, s2, proj, gamma, beta, sclB, shfB);

  k_gemm2<<<C_ * 4, 256, 0, stream>>>(hbuf, w2t, proj, perm, b2, sclB, shfB, out);

  k_mask<<<B_ * C_ / 256, 256, 0, stream>>>(mask, out + (size_t)B_ * C_ * O_);
}

// Round 3
// 160.325 us; speedup vs baseline: 1.4329x; 1.1358x over previous
//
#include <hip/hip_runtime.h>

typedef unsigned short u16;
typedef unsigned int   u32;
typedef __attribute__((ext_vector_type(8))) short s16x8;
typedef __attribute__((ext_vector_type(4))) float f32x4;
typedef __attribute__((ext_vector_type(4))) u32   u32x4;

#define DEV static __device__ __forceinline__

static constexpr int B_ = 256, C_ = 64, D_ = 256, H_ = 4096, O_ = 256, E_ = 4;

DEV u16 f2bf(float f) {
  u32 u = __builtin_bit_cast(u32, f);
  u += 0x7fffu + ((u >> 16) & 1u);   // RNE
  return (u16)(u >> 16);
}
DEV float bf2f(u16 u) { return __builtin_bit_cast(float, (u32)u << 16); }

DEV void async16(const u16* g, u16* l) {
  __builtin_amdgcn_global_load_lds(
      (const __attribute__((address_space(1))) void*)g,
      (__attribute__((address_space(3))) void*)l, 16, 0, 0);
}

DEV int xcd_swz(int bid, int nwg) { return (bid & 7) * (nwg >> 3) + (bid >> 3); }

// ---------------- convert f32 -> bf16, 8 elems/thread ----------------
__global__ void k_cvt(const float* __restrict__ src, u16* __restrict__ dst) {
  const int i = blockIdx.x * blockDim.x + threadIdx.x;
  const f32x4 a = ((const f32x4*)src)[2 * i];
  const f32x4 b = ((const f32x4*)src)[2 * i + 1];
  u32x4 o;
  o[0] = (u32)f2bf(a[0]) | ((u32)f2bf(a[1]) << 16);
  o[1] = (u32)f2bf(a[2]) | ((u32)f2bf(a[3]) << 16);
  o[2] = (u32)f2bf(b[0]) | ((u32)f2bf(b[1]) << 16);
  o[3] = (u32)f2bf(b[2]) | ((u32)f2bf(b[3]) << 16);
  ((u32x4*)dst)[i] = o;
}

// ------------- per-expert slab transpose: f32 [R][C] -> bf16 [C][R] -------------
__global__ void k_transpose(const float* __restrict__ src, u16* __restrict__ dst,
                            const int R, const int Cc) {
  __shared__ float tile[64][65];
  const int nct = Cc >> 6, nrt = R >> 6;
  int bx = blockIdx.x;
  const int ct = bx % nct; bx /= nct;
  const int rt = bx % nrt; const int e = bx / nrt;
  const float* s = src + (size_t)e * R * Cc;
  u16* d = dst + (size_t)e * R * Cc;
  const int tx = threadIdx.x & 63, ty = threadIdx.x >> 6;
  #pragma unroll
  for (int i = 0; i < 64; i += 4)
    tile[i + ty][tx] = s[(size_t)(rt * 64 + i + ty) * Cc + ct * 64 + tx];
  __syncthreads();
  #pragma unroll
  for (int i = 0; i < 64; i += 4) {
    const int cc = i + ty;
    d[(size_t)(ct * 64 + cc) * R + rt * 64 + tx] = f2bf(tile[tx][cc]);
  }
}

// ---------------- channel rank by expert (deterministic counting sort) ----------------
__global__ void k_sortc(const int* __restrict__ proj, int* __restrict__ perm) {
  const int c = threadIdx.x;              // 64 threads
  const int e = proj[c];
  int rank = 0;
  for (int c2 = 0; c2 < C_; ++c2) {
    const int e2 = proj[c2];
    rank += (e2 < e) || (e2 == e && c2 < c);
  }
  perm[rank] = c;
}

// ---------------- GEMM1: h = x*W1 + b1, fused per-expert sum/sumsq ----------------
// A: x bf16 token-major; Bw: w1t [E][H][D] (K=D contiguous). BK=32, 32KB LDS, 4 blk/CU.
__global__ __launch_bounds__(256, 4)
void k_gemm1(const u16* __restrict__ A, const u16* __restrict__ Bw,
             const int* __restrict__ proj, const int* __restrict__ perm,
             const float* __restrict__ bias,
             u16* __restrict__ outH, float* __restrict__ s1g, float* __restrict__ s2g) {
  constexpr int BM = 128, BN = 128, BK = 32, KT = D_ / BK;   // 8 K-steps
  constexpr int SA = BM * BK / 8, SB = BN * BK / 8;          // 512, 512 16B-slots
  constexpr int BUF = (SA + SB) * 8;                         // u16 per buffer (16KB)
  __shared__ __align__(16) u16 lds[2 * BUF];                 // 32 KB
  const int tid = threadIdx.x, l = tid & 63, w = tid >> 6, wm = w >> 1, wn = w & 1;

  int bid = xcd_swz(blockIdx.x, gridDim.x);
  constexpr int NT = H_ / BN, BT = B_ / BM;                  // 32, 2
  const int nt = bid % NT; bid /= NT;
  const int bt = bid % BT; const int ci = bid / BT;
  const int c = perm[ci];
  const int e = proj[c];

  const size_t rsA = (size_t)C_ * D_;
  const u16* Ab = A + (size_t)c * D_ + (size_t)bt * BM * rsA;
  const u16* Bb = Bw + ((size_t)e * H_ + (size_t)nt * BN) * D_;

  f32x4 acc[4][4] = {};

  auto stage = [&](int kt) {
    const int k0 = kt * BK;
    u16* dst = lds + (kt & 1) * BUF;
    #pragma unroll
    for (int i = 0; i < SA / 256; ++i) {
      const int s = i * 256 + tid, row = s >> 2, j = (s & 3) ^ (row & 3);
      async16(Ab + (size_t)row * rsA + k0 + j * 8, dst + s * 8);
    }
    #pragma unroll
    for (int i = 0; i < SB / 256; ++i) {
      const int s = i * 256 + tid, col = s >> 2, j = (s & 3) ^ (col & 3);
      async16(Bb + (size_t)col * D_ + k0 + j * 8, dst + SA * 8 + s * 8);
    }
  };

  stage(0);
  asm volatile("s_waitcnt vmcnt(0)" ::: "memory");
  __builtin_amdgcn_s_barrier();

  #pragma unroll
  for (int kt = 0; kt < KT; ++kt) {
    if (kt + 1 < KT) stage(kt + 1);          // prefetch overlaps compute below
    const u16* bufA = lds + (kt & 1) * BUF;
    const u16* bufB = bufA + SA * 8;
    s16x8 av[4], bv[4];
    #pragma unroll
    for (int m = 0; m < 4; ++m) {
      const int r = wm * 64 + m * 16 + (l & 15), p = (l >> 4) ^ (r & 3);
      av[m] = *(const s16x8*)(bufA + (r * 4 + p) * 8);
    }
    #pragma unroll
    for (int n = 0; n < 4; ++n) {
      const int cc = wn * 64 + n * 16 + (l & 15), p = (l >> 4) ^ (cc & 3);
      bv[n] = *(const s16x8*)(bufB + (cc * 4 + p) * 8);
    }
    #pragma unroll
    for (int m = 0; m < 4; ++m)
      #pragma unroll
      for (int n = 0; n < 4; ++n)
        acc[m][n] = __builtin_amdgcn_mfma_f32_16x16x32_bf16(av[m], bv[n], acc[m][n], 0, 0, 0);
    asm volatile("s_waitcnt vmcnt(0) lgkmcnt(0)" ::: "memory");
    __builtin_amdgcn_s_barrier();
  }

  // epilogue: bias + stats + bf16 pack into LDS (XOR 16B-slot swizzle), then 16B stores
  u16* ldsOut = lds;   // 32 KB region, free after final barrier
  #pragma unroll
  for (int n = 0; n < 4; ++n) {
    const int colL = wn * 64 + n * 16 + (l & 15);
    const int colg = nt * BN + colL;
    const float bval = bias[e * H_ + colg];
    float p1 = 0.f, p2 = 0.f;
    #pragma unroll
    for (int m = 0; m < 4; ++m) {
      const int rbase = wm * 64 + m * 16 + (l >> 4) * 4;
      #pragma unroll
      for (int i = 0; i < 4; ++i) {
        const float v = acc[m][n][i] + bval;
        p1 += v; p2 += v * v;
        const int row = rbase + i;
        const int phys = (colL >> 3) ^ (row & 15);
        ldsOut[row * 128 + phys * 8 + (colL & 7)] = f2bf(v);
      }
    }
    p1 += __shfl_xor(p1, 16); p1 += __shfl_xor(p1, 32);
    p2 += __shfl_xor(p2, 16); p2 += __shfl_xor(p2, 32);
    if (l < 16) {
      atomicAdd(&s1g[e * H_ + colg], p1);
      atomicAdd(&s2g[e * H_ + colg], p2);
    }
  }
  __syncthreads();
  u16* outB = outH + ((size_t)(bt * BM) * C_ + c) * H_ + nt * BN;
  #pragma unroll
  for (int pass = 0; pass < 8; ++pass) {
    const int row = pass * 16 + (tid >> 4), sl = tid & 15;
    const u32x4 v = *(const u32x4*)(ldsOut + row * 128 + ((sl ^ (row & 15)) * 8));
    *(u32x4*)(outB + (size_t)row * C_ * H_ + sl * 8) = v;
  }
}

// ---------------- BN finalize -> bf16 scale/shift ----------------
__global__ void k_finalize(const float* __restrict__ s1, const float* __restrict__ s2,
                           const int* __restrict__ proj, const float* __restrict__ gamma,
                           const float* __restrict__ beta,
                           u16* __restrict__ sclB, u16* __restrict__ shfB) {
  const int i = blockIdx.x * 256 + threadIdx.x;   // over E*H
  const int e = i >> 12;                          // H = 4096
  int cn = 0;
  #pragma unroll
  for (int c = 0; c < C_; ++c) cn += (proj[c] == e) ? 1 : 0;
  const float cnt = fmaxf((float)cn * (float)B_, 1.f);
  const float mean = s1[i] / cnt;
  const float var = s2[i] / cnt - mean * mean;    // biased (train-mode BN)
  const float sc = rsqrtf(var + 1e-5f) * gamma[i];
  sclB[i] = f2bf(sc);
  shfB[i] = f2bf(beta[i] - mean * sc);
}

// ---------------- GEMM2: out = relu(scale*h+shift)*W2 + b2, split-K=2 ----------------
// A: h bf16 token-major; Bw: w2t [E][O][H] (K=H contiguous). 128x128 tile, KS=2.
__global__ __launch_bounds__(256, 2)
void k_gemm2(const u16* __restrict__ A, const u16* __restrict__ Bw,
             const int* __restrict__ proj, const int* __restrict__ perm,
             const float* __restrict__ b2,
             const u16* __restrict__ scB, const u16* __restrict__ shB,
             float* __restrict__ outF, float* __restrict__ partial) {
  constexpr int BM = 128, BN = 128, BK = 64, KH = H_ / 2, KT = KH / BK;  // 32 K-steps
  constexpr int SA = BM * BK / 8, SB = BN * BK / 8;          // 1024, 1024
  constexpr int BUF = (SA + SB) * 8;                         // 32 KB
  __shared__ __align__(16) u16 lds[2 * BUF];                 // 64 KB
  const int tid = threadIdx.x, l = tid & 63, w = tid >> 6, wm = w >> 1, wn = w & 1;

  int bid = xcd_swz(blockIdx.x, gridDim.x);
  const int ks = bid & 1; bid >>= 1;
  const int nt = bid & 1; bid >>= 1;
  const int bt = bid & 1; const int ci = bid >> 1;
  const int c = perm[ci];
  const int e = proj[c];

  const size_t rsA = (size_t)C_ * H_;
  const u16* Ab = A + (size_t)c * H_ + (size_t)bt * BM * rsA + (size_t)ks * KH;
  const u16* Bb = Bw + ((size_t)e * O_ + (size_t)nt * BN) * H_ + (size_t)ks * KH;
  const u16* scE = scB + e * H_ + ks * KH;
  const u16* shE = shB + e * H_ + ks * KH;

  f32x4 acc[4][4] = {};
  s16x8 hA[4], sA[4], tA[4];

  auto Aissue = [&](int kt) {          // issue-early: h + scale + shift to regs
    const int k0 = kt * BK;
    #pragma unroll
    for (int i = 0; i < 4; ++i) {
      const int s = i * 256 + tid, row = s >> 3, j = (s & 7) ^ (row & 7), k = k0 + j * 8;
      hA[i] = *(const s16x8*)(Ab + (size_t)row * rsA + k);
      sA[i] = *(const s16x8*)(scE + k);
      tA[i] = *(const s16x8*)(shE + k);
    }
  };
  auto Bissue = [&](int kt) {
    const int k0 = kt * BK;
    u16* dst = lds + (kt & 1) * BUF + SA * 8;
    #pragma unroll
    for (int i = 0; i < 4; ++i) {
      const int s = i * 256 + tid, col = s >> 3, j = (s & 7) ^ (col & 7);
      async16(Bb + (size_t)col * H_ + k0 + j * 8, dst + s * 8);
    }
  };
  auto Awrite = [&](int kt) {          // write-late: BN apply + ReLU + bf16 pack
    u16* dst = lds + (kt & 1) * BUF;
    #pragma unroll
    for (int i = 0; i < 4; ++i) {
      const int s = i * 256 + tid;
      u32x4 o;
      #pragma unroll
      for (int jj = 0; jj < 4; ++jj) {
        const float v0 = fmaxf(bf2f((u16)hA[i][2 * jj]) * bf2f((u16)sA[i][2 * jj]) + bf2f((u16)tA[i][2 * jj]), 0.f);
        const float v1 = fmaxf(bf2f((u16)hA[i][2 * jj + 1]) * bf2f((u16)sA[i][2 * jj + 1]) + bf2f((u16)tA[i][2 * jj + 1]), 0.f);
        o[jj] = (u32)f2bf(v0) | ((u32)f2bf(v1) << 16);
      }
      *(u32x4*)(dst + s * 8) = o;
    }
  };

  Aissue(0); Bissue(0); Awrite(0);
  asm volatile("s_waitcnt vmcnt(0) lgkmcnt(0)" ::: "memory");
  __builtin_amdgcn_s_barrier();

  #pragma unroll 2
  for (int kt = 0; kt < KT; ++kt) {
    if (kt + 1 < KT) { Aissue(kt + 1); Bissue(kt + 1); }
    const u16* bufA = lds + (kt & 1) * BUF;
    const u16* bufB = bufA + SA * 8;
    s16x8 av[2][4], bv[2][4];
    #pragma unroll
    for (int kk = 0; kk < 2; ++kk) {
      #pragma unroll
      for (int m = 0; m < 4; ++m) {
        const int r = wm * 64 + m * 16 + (l & 15), p = (kk * 4 + (l >> 4)) ^ (r & 7);
        av[kk][m] = *(const s16x8*)(bufA + (r * 8 + p) * 8);
      }
      #pragma unroll
      for (int n = 0; n < 4; ++n) {
        const int cc = wn * 64 + n * 16 + (l & 15), p = (kk * 4 + (l >> 4)) ^ (cc & 7);
        bv[kk][n] = *(const s16x8*)(bufB + (cc * 8 + p) * 8);
      }
    }
    #pragma unroll
    for (int kk = 0; kk < 2; ++kk)
      #pragma unroll
      for (int m = 0; m < 4; ++m)
        #pragma unroll
        for (int n = 0; n < 4; ++n)
          acc[m][n] = __builtin_amdgcn_mfma_f32_16x16x32_bf16(av[kk][m], bv[kk][n], acc[m][n], 0, 0, 0);
    if (kt + 1 < KT) Awrite(kt + 1);
    asm volatile("s_waitcnt vmcnt(0) lgkmcnt(0)" ::: "memory");
    __builtin_amdgcn_s_barrier();
  }

  float* dstF = ks ? partial : outF;
  #pragma unroll
  for (int n = 0; n < 4; ++n) {
    const int colg = nt * BN + wn * 64 + n * 16 + (l & 15);
    const float bval = ks ? 0.f : b2[e * O_ + colg];
    #pragma unroll
    for (int m = 0; m < 4; ++m) {
      #pragma unroll
      for (int i = 0; i < 4; ++i) {
        const int rg = bt * BM + wm * 64 + m * 16 + (l >> 4) * 4 + i;
        dstF[((size_t)rg * C_ + c) * O_ + colg] = acc[m][n][i] + bval;
      }
    }
  }
}

// ---------------- combine split-K partials + mask passthrough ----------------
__global__ void k_combine(float* __restrict__ out, const float* __restrict__ partial,
                          const int* __restrict__ mask, float* __restrict__ maskOut) {
  const int gi = blockIdx.x * 256 + threadIdx.x;     // 8 floats each
  const size_t b = (size_t)gi * 2;
  f32x4 a0 = ((const f32x4*)out)[b],     a1 = ((const f32x4*)out)[b + 1];
  const f32x4 p0 = ((const f32x4*)partial)[b], p1 = ((const f32x4*)partial)[b + 1];
  #pragma unroll
  for (int j = 0; j < 4; ++j) { a0[j] += p0[j]; a1[j] += p1[j]; }
  ((f32x4*)out)[b] = a0; ((f32x4*)out)[b + 1] = a1;
  if (gi < B_ * C_ / 8) {
    #pragma unroll
    for (int j = 0; j < 8; ++j) maskOut[gi * 8 + j] = (float)mask[gi * 8 + j];
  }
}

extern "C" void kernel_launch(void* const* d_in, const int* in_sizes, int n_in,
                              void* d_out, int out_size, void* d_ws, size_t ws_size,
                              hipStream_t stream) {
  const float* x     = (const float*)d_in[0];
  const int*   mask  = (const int*)d_in[1];
  const int*   proj  = (const int*)d_in[2];
  const float* W1    = (const float*)d_in[3];
  const float* b1    = (const float*)d_in[4];
  const float* gamma = (const float*)d_in[5];
  const float* beta  = (const float*)d_in[6];
  const float* W2    = (const float*)d_in[7];
  const float* b2    = (const float*)d_in[8];
  float* out = (float*)d_out;

  char* ws = (char*)d_ws;
  size_t off = 0;
  u16* hbuf = (u16*)(ws + off); off += (size_t)B_ * C_ * H_ * 2;   // 128 MB
  u16* xb   = (u16*)(ws + off); off += (size_t)B_ * C_ * D_ * 2;   // 8 MB
  u16* w1t  = (u16*)(ws + off); off += (size_t)E_ * D_ * H_ * 2;   // 8 MB  [E][H][D]
  // partial (16 MB f32) aliases xb+w1t — both dead after k_gemm1.
  float* partial = (float*)xb;
  u16* w2t  = (u16*)(ws + off); off += (size_t)E_ * H_ * O_ * 2;   // 8 MB  [E][O][H]
  float* s1 = (float*)(ws + off); off += (size_t)E_ * H_ * 4;
  float* s2 = (float*)(ws + off); off += (size_t)E_ * H_ * 4;
  u16* sclB = (u16*)(ws + off); off += (size_t)E_ * H_ * 2;
  u16* shfB = (u16*)(ws + off); off += (size_t)E_ * H_ * 2;
  int* perm = (int*)(ws + off); off += 256;

  (void)hipMemsetAsync(s1, 0, (size_t)2 * E_ * H_ * 4, stream);   // s1+s2 contiguous

  k_sortc<<<1, 64, 0, stream>>>(proj, perm);
  k_cvt<<<2048, 256, 0, stream>>>(x, xb);
  k_transpose<<<E_ * 4 * 64, 256, 0, stream>>>(W1, w1t, D_, H_);   // [D][H]->[H][D]
  k_transpose<<<E_ * 64 * 4, 256, 0, stream>>>(W2, w2t, H_, O_);   // [H][O]->[O][H]

  k_gemm1<<<C_ * 2 * 32, 256, 0, stream>>>(xb, w1t, proj, perm, b1, hbuf, s1, s2);

  k_finalize<<<E_ * H_ / 256, 256, 0, stream>>>(s1, s2, proj, gamma, beta, sclB, shfB);

  // grid = C * BT * NT * KS = 64*2*2*2 = 512 blocks
  k_gemm2<<<512, 256, 0, stream>>>(hbuf, w2t, proj, perm, b2, sclB, shfB, out, partial);

  k_combine<<<B_ * C_ * O_ / 8 / 256, 256, 0, stream>>>(out, partial, mask,
                                                        out + (size_t)B_ * C_ * O_);
}

// Round 6
// 160.063 us; speedup vs baseline: 1.4353x; 1.0016x over previous
//
#include <hip/hip_runtime.h>

typedef unsigned short u16;
typedef unsigned int   u32;
typedef __attribute__((ext_vector_type(8))) short s16x8;
typedef __attribute__((ext_vector_type(4))) float f32x4;
typedef __attribute__((ext_vector_type(4))) u32   u32x4;

#define DEV static __device__ __forceinline__

static constexpr int B_ = 256, C_ = 64, D_ = 256, H_ = 4096, O_ = 256, E_ = 4;

DEV u16 f2bf(float f) {
  u32 u = __builtin_bit_cast(u32, f);
  u += 0x7fffu + ((u >> 16) & 1u);   // RNE
  return (u16)(u >> 16);
}
DEV float bf2f(u16 u) { return __builtin_bit_cast(float, (u32)u << 16); }

DEV void async16(const u16* g, u16* l) {
  __builtin_amdgcn_global_load_lds(
      (const __attribute__((address_space(1))) void*)g,
      (__attribute__((address_space(3))) void*)l, 16, 0, 0);
}

DEV int xcd_swz(int bid, int nwg) { return (bid & 7) * (nwg >> 3) + (bid >> 3); }

// ---------------- convert f32 -> bf16, 8 elems/thread ----------------
__global__ void k_cvt(const float* __restrict__ src, u16* __restrict__ dst) {
  const int i = blockIdx.x * blockDim.x + threadIdx.x;
  const f32x4 a = ((const f32x4*)src)[2 * i];
  const f32x4 b = ((const f32x4*)src)[2 * i + 1];
  u32x4 o;
  o[0] = (u32)f2bf(a[0]) | ((u32)f2bf(a[1]) << 16);
  o[1] = (u32)f2bf(a[2]) | ((u32)f2bf(a[3]) << 16);
  o[2] = (u32)f2bf(b[0]) | ((u32)f2bf(b[1]) << 16);
  o[3] = (u32)f2bf(b[2]) | ((u32)f2bf(b[3]) << 16);
  ((u32x4*)dst)[i] = o;
}

// ------------- per-expert slab transpose: f32 [R][C] -> bf16 [C][R] -------------
__global__ void k_transpose(const float* __restrict__ src, u16* __restrict__ dst,
                            const int R, const int Cc) {
  __shared__ float tile[64][65];
  const int nct = Cc >> 6, nrt = R >> 6;
  int bx = blockIdx.x;
  const int ct = bx % nct; bx /= nct;
  const int rt = bx % nrt; const int e = bx / nrt;
  const float* s = src + (size_t)e * R * Cc;
  u16* d = dst + (size_t)e * R * Cc;
  const int tx = threadIdx.x & 63, ty = threadIdx.x >> 6;
  #pragma unroll
  for (int i = 0; i < 64; i += 4)
    tile[i + ty][tx] = s[(size_t)(rt * 64 + i + ty) * Cc + ct * 64 + tx];
  __syncthreads();
  #pragma unroll
  for (int i = 0; i < 64; i += 4) {
    const int cc = i + ty;
    d[(size_t)(ct * 64 + cc) * R + rt * 64 + tx] = f2bf(tile[tx][cc]);
  }
}

// ---------------- channel rank by expert (deterministic counting sort) ----------------
__global__ void k_sortc(const int* __restrict__ proj, int* __restrict__ perm) {
  const int c = threadIdx.x;              // 64 threads
  const int e = proj[c];
  int rank = 0;
  for (int c2 = 0; c2 < C_; ++c2) {
    const int e2 = proj[c2];
    rank += (e2 < e) || (e2 == e && c2 < c);
  }
  perm[rank] = c;
}

// ---------------- GEMM1: h = x*W1 + b1, fused per-expert sum/sumsq ----------------
// ROUND-3 VERSION (verified passing): 2-buffer, vmcnt(0) drain per step. BK=32.
__global__ __launch_bounds__(256, 4)
void k_gemm1(const u16* __restrict__ A, const u16* __restrict__ Bw,
             const int* __restrict__ proj, const int* __restrict__ perm,
             const float* __restrict__ bias,
             u16* __restrict__ outH, float* __restrict__ s1g, float* __restrict__ s2g) {
  constexpr int BM = 128, BN = 128, BK = 32, KT = D_ / BK;   // 8 K-steps
  constexpr int SA = BM * BK / 8, SB = BN * BK / 8;          // 512, 512 16B-slots
  constexpr int BUF = (SA + SB) * 8;                         // 8192 u16 (16KB)
  __shared__ __align__(16) u16 lds[2 * BUF];                 // 32 KB
  const int tid = threadIdx.x, l = tid & 63, w = tid >> 6, wm = w >> 1, wn = w & 1;

  int bid = xcd_swz(blockIdx.x, gridDim.x);
  constexpr int NT = H_ / BN, BT = B_ / BM;                  // 32, 2
  const int nt = bid % NT; bid /= NT;
  const int bt = bid % BT; const int ci = bid / BT;
  const int c = perm[ci];
  const int e = proj[c];

  const size_t rsA = (size_t)C_ * D_;
  const u16* Ab = A + (size_t)c * D_ + (size_t)bt * BM * rsA;
  const u16* Bb = Bw + ((size_t)e * H_ + (size_t)nt * BN) * D_;

  f32x4 acc[4][4] = {};

  auto stage = [&](int kt) {           // 4 glds per thread (2 A + 2 B)
    const int k0 = kt * BK;
    u16* dst = lds + (kt & 1) * BUF;
    #pragma unroll
    for (int i = 0; i < 2; ++i) {
      const int s = i * 256 + tid, row = s >> 2, j = (s & 3) ^ (row & 3);
      async16(Ab + (size_t)row * rsA + k0 + j * 8, dst + s * 8);
    }
    #pragma unroll
    for (int i = 0; i < 2; ++i) {
      const int s = i * 256 + tid, col = s >> 2, j = (s & 3) ^ (col & 3);
      async16(Bb + (size_t)col * D_ + k0 + j * 8, dst + SA * 8 + s * 8);
    }
  };

  stage(0);
  asm volatile("s_waitcnt vmcnt(0)" ::: "memory");
  __builtin_amdgcn_s_barrier();

  #pragma unroll
  for (int kt = 0; kt < KT; ++kt) {
    if (kt + 1 < KT) stage(kt + 1);          // prefetch overlaps compute below
    const u16* bufA = lds + (kt & 1) * BUF;
    const u16* bufB = bufA + SA * 8;
    s16x8 av[4], bv[4];
    #pragma unroll
    for (int m = 0; m < 4; ++m) {
      const int r = wm * 64 + m * 16 + (l & 15), p = (l >> 4) ^ (r & 3);
      av[m] = *(const s16x8*)(bufA + (r * 4 + p) * 8);
    }
    #pragma unroll
    for (int n = 0; n < 4; ++n) {
      const int cc = wn * 64 + n * 16 + (l & 15), p = (l >> 4) ^ (cc & 3);
      bv[n] = *(const s16x8*)(bufB + (cc * 4 + p) * 8);
    }
    #pragma unroll
    for (int m = 0; m < 4; ++m)
      #pragma unroll
      for (int n = 0; n < 4; ++n)
        acc[m][n] = __builtin_amdgcn_mfma_f32_16x16x32_bf16(av[m], bv[n], acc[m][n], 0, 0, 0);
    asm volatile("s_waitcnt vmcnt(0) lgkmcnt(0)" ::: "memory");
    __builtin_amdgcn_s_barrier();
  }

  // epilogue: bias + stats + bf16 pack into LDS (XOR 16B-slot swizzle), then 16B stores
  u16* ldsOut = lds;
  #pragma unroll
  for (int n = 0; n < 4; ++n) {
    const int colL = wn * 64 + n * 16 + (l & 15);
    const int colg = nt * BN + colL;
    const float bval = bias[e * H_ + colg];
    float p1 = 0.f, p2 = 0.f;
    #pragma unroll
    for (int m = 0; m < 4; ++m) {
      const int rbase = wm * 64 + m * 16 + (l >> 4) * 4;
      #pragma unroll
      for (int i = 0; i < 4; ++i) {
        const float v = acc[m][n][i] + bval;
        p1 += v; p2 += v * v;
        const int row = rbase + i;
        const int phys = (colL >> 3) ^ (row & 15);
        ldsOut[row * 128 + phys * 8 + (colL & 7)] = f2bf(v);
      }
    }
    p1 += __shfl_xor(p1, 16); p1 += __shfl_xor(p1, 32);
    p2 += __shfl_xor(p2, 16); p2 += __shfl_xor(p2, 32);
    if (l < 16) {
      atomicAdd(&s1g[e * H_ + colg], p1);
      atomicAdd(&s2g[e * H_ + colg], p2);
    }
  }
  __syncthreads();
  u16* outB = outH + ((size_t)(bt * BM) * C_ + c) * H_ + nt * BN;
  #pragma unroll
  for (int pass = 0; pass < 8; ++pass) {
    const int row = pass * 16 + (tid >> 4), sl = tid & 15;
    const u32x4 v = *(const u32x4*)(ldsOut + row * 128 + ((sl ^ (row & 15)) * 8));
    *(u32x4*)(outB + (size_t)row * C_ * H_ + sl * 8) = v;
  }
}

// ---------------- BN finalize -> bf16 scale/shift ----------------
__global__ void k_finalize(const float* __restrict__ s1, const float* __restrict__ s2,
                           const int* __restrict__ proj, const float* __restrict__ gamma,
                           const float* __restrict__ beta,
                           u16* __restrict__ sclB, u16* __restrict__ shfB) {
  const int i = blockIdx.x * 256 + threadIdx.x;   // over E*H
  const int e = i >> 12;                          // H = 4096
  int cn = 0;
  #pragma unroll
  for (int c = 0; c < C_; ++c) cn += (proj[c] == e) ? 1 : 0;
  const float cnt = fmaxf((float)cn * (float)B_, 1.f);
  const float mean = s1[i] / cnt;
  const float var = s2[i] / cnt - mean * mean;    // biased (train-mode BN)
  const float sc = rsqrtf(var + 1e-5f) * gamma[i];
  sclB[i] = f2bf(sc);
  shfB[i] = f2bf(beta[i] - mean * sc);
}

// ---------------- GEMM2: out = relu(scale*h+shift)*W2 + b2, split-K=2 ----------------
// Fully reg-staged pipeline (NO global_load_lds in the loop): A and B both go
// global->VGPR->ds_write. LDS readiness ordered by lgkmcnt(0)+barrier only;
// VMEM completion enforced by compiler register-dep waits on a homogeneous
// load stream. 3 LDS buffers, loads issued 2 steps ahead into ping-pong regs.
__global__ __launch_bounds__(256, 2)
void k_gemm2(const u16* __restrict__ A, const u16* __restrict__ Bw,
             const int* __restrict__ proj, const int* __restrict__ perm,
             const float* __restrict__ b2,
             const u16* __restrict__ scB, const u16* __restrict__ shB,
             float* __restrict__ outF, float* __restrict__ partial) {
  constexpr int BM = 128, BN = 128, BK = 32, KH = H_ / 2, KT = KH / BK;  // 64 K-steps
  constexpr int SA = BM * BK / 8, SB = BN * BK / 8;          // 512, 512
  constexpr int BUF = (SA + SB) * 8;                         // 8192 u16 (16KB)
  __shared__ __align__(16) u16 lds[3 * BUF + 2 * KH];        // 48 + 8 KB
  u16* stS = lds + 3 * BUF;          // scale[KH]
  u16* stT = stS + KH;               // shift[KH]
  const int tid = threadIdx.x, l = tid & 63, w = tid >> 6, wm = w >> 1, wn = w & 1;

  int bid = xcd_swz(blockIdx.x, gridDim.x);
  const int ks = bid & 1; bid >>= 1;
  const int nt = bid & 1; bid >>= 1;
  const int bt = bid & 1; const int ci = bid >> 1;
  const int c = perm[ci];
  const int e = proj[c];

  const size_t rsA = (size_t)C_ * H_;
  const u16* Ab = A + (size_t)c * H_ + (size_t)bt * BM * rsA + (size_t)ks * KH;
  const u16* Bb = Bw + ((size_t)e * O_ + (size_t)nt * BN) * H_ + (size_t)ks * KH;
  const u16* scE = scB + e * H_ + ks * KH;
  const u16* shE = shB + e * H_ + ks * KH;

  f32x4 acc[4][4] = {};
  s16x8 h0[2], h1[2], b0r[2], b1r[2];  // ping-pong reg sets; step k lives in set k%2

  auto Aissue = [&](int kt, s16x8 (&hs)[2]) {
    const int k0 = kt * BK;
    #pragma unroll
    for (int i = 0; i < 2; ++i) {
      const int s = i * 256 + tid, row = s >> 2, j = (s & 3) ^ (row & 3);
      hs[i] = *(const s16x8*)(Ab + (size_t)row * rsA + k0 + j * 8);
    }
  };
  auto Bissue = [&](int kt, s16x8 (&bs)[2]) {
    const int k0 = kt * BK;
    #pragma unroll
    for (int i = 0; i < 2; ++i) {
      const int s = i * 256 + tid, col = s >> 2, j = (s & 3) ^ (col & 3);
      bs[i] = *(const s16x8*)(Bb + (size_t)col * H_ + k0 + j * 8);
    }
  };
  auto Awrite = [&](int kt, s16x8 (&hs)[2]) {   // BN apply + ReLU + bf16 pack -> LDS
    u16* dst = lds + (kt % 3) * BUF;
    const int k0 = kt * BK;
    #pragma unroll
    for (int i = 0; i < 2; ++i) {
      const int s = i * 256 + tid, row = s >> 2, j = (s & 3) ^ (row & 3);
      const s16x8 sv = *(const s16x8*)(stS + k0 + j * 8);   // broadcast ds_read
      const s16x8 tv = *(const s16x8*)(stT + k0 + j * 8);
      u32x4 o;
      #pragma unroll
      for (int jj = 0; jj < 4; ++jj) {
        const float v0 = fmaxf(bf2f((u16)hs[i][2 * jj]) * bf2f((u16)sv[2 * jj]) + bf2f((u16)tv[2 * jj]), 0.f);
        const float v1 = fmaxf(bf2f((u16)hs[i][2 * jj + 1]) * bf2f((u16)sv[2 * jj + 1]) + bf2f((u16)tv[2 * jj + 1]), 0.f);
        o[jj] = (u32)f2bf(v0) | ((u32)f2bf(v1) << 16);
      }
      *(u32x4*)(dst + s * 8) = o;
    }
  };
  auto Bwrite = [&](int kt, s16x8 (&bs)[2]) {   // raw pass-through -> LDS
    u16* dst = lds + (kt % 3) * BUF + SA * 8;
    #pragma unroll
    for (int i = 0; i < 2; ++i) {
      const int s = i * 256 + tid;
      *(u32x4*)(dst + s * 8) = __builtin_bit_cast(u32x4, bs[i]);
    }
  };
  auto Compute = [&](int kt) {
    const u16* bufA = lds + (kt % 3) * BUF;
    const u16* bufB = bufA + SA * 8;
    s16x8 av[4], bv[4];
    #pragma unroll
    for (int m = 0; m < 4; ++m) {
      const int r = wm * 64 + m * 16 + (l & 15), p = (l >> 4) ^ (r & 3);
      av[m] = *(const s16x8*)(bufA + (r * 4 + p) * 8);
    }
    #pragma unroll
    for (int n = 0; n < 4; ++n) {
      const int cc = wn * 64 + n * 16 + (l & 15), p = (l >> 4) ^ (cc & 3);
      bv[n] = *(const s16x8*)(bufB + (cc * 4 + p) * 8);
    }
    #pragma unroll
    for (int m = 0; m < 4; ++m)
      #pragma unroll
      for (int n = 0; n < 4; ++n)
        acc[m][n] = __builtin_amdgcn_mfma_f32_16x16x32_bf16(av[m], bv[n], acc[m][n], 0, 0, 0);
  };

  // prologue: scale/shift DMA + first two steps' loads; ONE order-independent
  // full drain (vmcnt counter==0 covers mixed types regardless of return order).
  async16(scE + tid * 8, stS + tid * 8);
  async16(shE + tid * 8, stT + tid * 8);
  Aissue(0, h0); Bissue(0, b0r);
  Aissue(1, h1); Bissue(1, b1r);
  asm volatile("s_waitcnt vmcnt(0)" ::: "memory");
  Awrite(0, h0); Bwrite(0, b0r);
  asm volatile("s_waitcnt lgkmcnt(0)" ::: "memory");
  __builtin_amdgcn_s_barrier();

  // steady: {issue(s+2); write(s+1); compute(s); lgkmcnt(0); barrier}
  #pragma unroll 1
  for (int kt = 0; kt + 3 < KT; kt += 2) {
    Aissue(kt + 2, h0); Bissue(kt + 2, b0r);
    Awrite(kt + 1, h1); Bwrite(kt + 1, b1r);   // compiler waits on h1/b1 regs
    Compute(kt);
    asm volatile("s_waitcnt lgkmcnt(0)" ::: "memory");
    __builtin_amdgcn_s_barrier();
    Aissue(kt + 3, h1); Bissue(kt + 3, b1r);
    Awrite(kt + 2, h0); Bwrite(kt + 2, b0r);
    Compute(kt + 1);
    asm volatile("s_waitcnt lgkmcnt(0)" ::: "memory");
    __builtin_amdgcn_s_barrier();
  }

  // tail: steps KT-2 (buffer ready), KT-1 (write now from regs)
  Awrite(KT - 1, h1); Bwrite(KT - 1, b1r);
  Compute(KT - 2);
  asm volatile("s_waitcnt lgkmcnt(0)" ::: "memory");
  __builtin_amdgcn_s_barrier();
  Compute(KT - 1);

  float* dstF = ks ? partial : outF;
  #pragma unroll
  for (int n = 0; n < 4; ++n) {
    const int colg = nt * BN + wn * 64 + n * 16 + (l & 15);
    const float bval = ks ? 0.f : b2[e * O_ + colg];
    #pragma unroll
    for (int m = 0; m < 4; ++m) {
      #pragma unroll
      for (int i = 0; i < 4; ++i) {
        const int rg = bt * BM + wm * 64 + m * 16 + (l >> 4) * 4 + i;
        dstF[((size_t)rg * C_ + c) * O_ + colg] = acc[m][n][i] + bval;
      }
    }
  }
}

// ---------------- combine split-K partials + mask passthrough ----------------
__global__ void k_combine(float* __restrict__ out, const float* __restrict__ partial,
                          const int* __restrict__ mask, float* __restrict__ maskOut) {
  const int gi = blockIdx.x * 256 + threadIdx.x;     // 8 floats each
  const size_t b = (size_t)gi * 2;
  f32x4 a0 = ((const f32x4*)out)[b],     a1 = ((const f32x4*)out)[b + 1];
  const f32x4 p0 = ((const f32x4*)partial)[b], p1 = ((const f32x4*)partial)[b + 1];
  #pragma unroll
  for (int j = 0; j < 4; ++j) { a0[j] += p0[j]; a1[j] += p1[j]; }
  ((f32x4*)out)[b] = a0; ((f32x4*)out)[b + 1] = a1;
  if (gi < B_ * C_ / 8) {
    #pragma unroll
    for (int j = 0; j < 8; ++j) maskOut[gi * 8 + j] = (float)mask[gi * 8 + j];
  }
}

extern "C" void kernel_launch(void* const* d_in, const int* in_sizes, int n_in,
                              void* d_out, int out_size, void* d_ws, size_t ws_size,
                              hipStream_t stream) {
  const float* x     = (const float*)d_in[0];
  const int*   mask  = (const int*)d_in[1];
  const int*   proj  = (const int*)d_in[2];
  const float* W1    = (const float*)d_in[3];
  const float* b1    = (const float*)d_in[4];
  const float* gamma = (const float*)d_in[5];
  const float* beta  = (const float*)d_in[6];
  const float* W2    = (const float*)d_in[7];
  const float* b2    = (const float*)d_in[8];
  float* out = (float*)d_out;

  char* ws = (char*)d_ws;
  size_t off = 0;
  u16* hbuf = (u16*)(ws + off); off += (size_t)B_ * C_ * H_ * 2;   // 128 MB
  u16* xb   = (u16*)(ws + off); off += (size_t)B_ * C_ * D_ * 2;   // 8 MB
  u16* w1t  = (u16*)(ws + off); off += (size_t)E_ * D_ * H_ * 2;   // 8 MB  [E][H][D]
  // partial (16 MB f32) aliases xb+w1t — both dead after k_gemm1.
  float* partial = (float*)xb;
  u16* w2t  = (u16*)(ws + off); off += (size_t)E_ * H_ * O_ * 2;   // 8 MB  [E][O][H]
  float* s1 = (float*)(ws + off); off += (size_t)E_ * H_ * 4;
  float* s2 = (float*)(ws + off); off += (size_t)E_ * H_ * 4;
  u16* sclB = (u16*)(ws + off); off += (size_t)E_ * H_ * 2;
  u16* shfB = (u16*)(ws + off); off += (size_t)E_ * H_ * 2;
  int* perm = (int*)(ws + off); off += 256;

  (void)hipMemsetAsync(s1, 0, (size_t)2 * E_ * H_ * 4, stream);   // s1+s2 contiguous

  k_sortc<<<1, 64, 0, stream>>>(proj, perm);
  k_cvt<<<2048, 256, 0, stream>>>(x, xb);
  k_transpose<<<E_ * 4 * 64, 256, 0, stream>>>(W1, w1t, D_, H_);   // [D][H]->[H][D]
  k_transpose<<<E_ * 64 * 4, 256, 0, stream>>>(W2, w2t, H_, O_);   // [H][O]->[O][H]

  k_gemm1<<<C_ * 2 * 32, 256, 0, stream>>>(xb, w1t, proj, perm, b1, hbuf, s1, s2);

  k_finalize<<<E_ * H_ / 256, 256, 0, stream>>>(s1, s2, proj, gamma, beta, sclB, shfB);

  // grid = C * BT * NT * KS = 64*2*2*2 = 512 blocks
  k_gemm2<<<512, 256, 0, stream>>>(hbuf, w2t, proj, perm, b2, sclB, shfB, out, partial);

  k_combine<<<B_ * C_ * O_ / 8 / 256, 256, 0, stream>>>(out, partial, mask,
                                                        out + (size_t)B_ * C_ * O_);
}